// Round 17
// baseline (274.533 us; speedup 1.0000x reference)
//
#include <hip/hip_runtime.h>

// TransformerBlock: B=2, S=2048, D=1024, H=16, dh=64, FFN=4096.
// Round 17: pipe256 (256^2 tile, 8 waves, 32 MFMA/K-step/wave) for QKV+FFN1
// on the proven 3-deep counted-vmcnt loop. Rest = round 16.

typedef __attribute__((ext_vector_type(8))) short s16x8;
typedef __attribute__((ext_vector_type(4))) float f32x4;
typedef __attribute__((ext_vector_type(16))) float f32x16;
typedef unsigned short u16;
typedef unsigned int u32;

#define DEV static __device__ __forceinline__
#define MFMA16 __builtin_amdgcn_mfma_f32_16x16x32_bf16
#define MFMA32 __builtin_amdgcn_mfma_f32_32x32x16_bf16
#define GLOAD_LDS16(gp, lp)                                         \
  __builtin_amdgcn_global_load_lds(                                 \
      (const __attribute__((address_space(1))) void*)(gp),          \
      (__attribute__((address_space(3))) void*)(lp), 16, 0, 0)
#define WAIT_VM(N) asm volatile("s_waitcnt vmcnt(" #N ")" ::: "memory")

DEV u16 f2bf(float f) {
  union { float f; unsigned u; } c; c.f = f;
  unsigned u = c.u;
  u += 0x7fff + ((u >> 16) & 1);   // RNE
  return (u16)(u >> 16);
}

DEV u32 cvtpk(float lo, float hi) {  // packed f32x2 -> bf16x2 (RNE)
  u32 r;
  asm("v_cvt_pk_bf16_f32 %0, %1, %2" : "=v"(r) : "v"(lo), "v"(hi));
  return r;
}

DEV float frcp(float x) {
  float r;
  asm("v_rcp_f32 %0, %1" : "=v"(r) : "v"(x));
  return r;
}

// gelu(v) = v * sigmoid(2 c0 (v + a v^3)) = v / (1 + exp2(K v (1 + a v^2)))
DEV float gelu_tanh(float v) {
  const float K = -2.3021171648f;   // -2 * log2(e) * sqrt(2/pi)
  const float a = 0.044715f;
  const float w = v * v;
  const float q = fmaf(a, w, 1.0f);
  const float z = exp2f(K * v * q);
  return v * frcp(1.0f + z);
}

DEV s16x8 ld8(const u16* p) { return *(const s16x8*)p; }

// ---------- fused transpose+convert for all 6 weights ----------------------
DEV void tconv_tile(const float* __restrict__ W, u16* __restrict__ Wt, int K,
                    int N, int bx, int by, int t) {
  __shared__ u16 T[64][80];
  const int n0 = bx * 64, k0 = by * 64;
  const int kr = t >> 4, nc = (t & 15) * 4;
#pragma unroll
  for (int p = 0; p < 4; ++p) {
    const int k = p * 16 + kr;
    float4 v = *(const float4*)(W + (size_t)(k0 + k) * N + n0 + nc);
    T[nc + 0][k] = f2bf(v.x);
    T[nc + 1][k] = f2bf(v.y);
    T[nc + 2][k] = f2bf(v.z);
    T[nc + 3][k] = f2bf(v.w);
  }
  __syncthreads();
  const int nr = t >> 2, kc = (t & 3) * 16;
  *(s16x8*)(Wt + (size_t)(n0 + nr) * K + k0 + kc) = *(const s16x8*)&T[nr][kc];
  *(s16x8*)(Wt + (size_t)(n0 + nr) * K + k0 + kc + 8) =
      *(const s16x8*)&T[nr][kc + 8];
}

__global__ __launch_bounds__(256) void tconv_all(
    const float* __restrict__ wq, const float* __restrict__ wk,
    const float* __restrict__ wv, const float* __restrict__ wo,
    const float* __restrict__ w1, const float* __restrict__ w2,
    u16* __restrict__ qkvw, u16* __restrict__ wot, u16* __restrict__ w1t,
    u16* __restrict__ w2t) {
  const int idx = blockIdx.x, t = threadIdx.x;
  if (idx < 768) {
    const int which = idx >> 8, r = idx & 255;
    const float* W = which == 0 ? wq : (which == 1 ? wk : wv);
    tconv_tile(W, qkvw + which * 1048576, 1024, 1024, r & 15, r >> 4, t);
  } else if (idx < 1024) {
    const int r = idx - 768;
    tconv_tile(wo, wot, 1024, 1024, r & 15, r >> 4, t);
  } else if (idx < 2048) {
    const int r = idx - 1024;
    tconv_tile(w1, w1t, 1024, 4096, r & 63, r >> 6, t);
  } else {
    const int r = idx - 2048;
    tconv_tile(w2, w2t, 4096, 1024, r & 15, r >> 4, t);
  }
}

// ---------------- LayerNorm: fp32 [rows,1024] -> bf16 [rows,1024] ----------
__global__ __launch_bounds__(256) void ln_kernel(
    const float* __restrict__ x, const float* __restrict__ g,
    const float* __restrict__ b, u16* __restrict__ out) {
  const int row = blockIdx.x;
  const int t = threadIdx.x;
  const float* xr = x + (size_t)row * 1024;
  float4 v = *(const float4*)(xr + t * 4);
  float s = v.x + v.y + v.z + v.w;
  float ss = v.x * v.x + v.y * v.y + v.z * v.z + v.w * v.w;
#pragma unroll
  for (int off = 1; off < 64; off <<= 1) {
    s += __shfl_xor(s, off);
    ss += __shfl_xor(ss, off);
  }
  __shared__ float sb[4], ssb[4];
  const int w = t >> 6;
  if ((t & 63) == 0) { sb[w] = s; ssb[w] = ss; }
  __syncthreads();
  s = sb[0] + sb[1] + sb[2] + sb[3];
  ss = ssb[0] + ssb[1] + ssb[2] + ssb[3];
  const float mean = s * (1.0f / 1024.0f);
  const float var = ss * (1.0f / 1024.0f) - mean * mean;
  const float rstd = rsqrtf(var + 1e-5f);
  const int c = t * 4;
  ushort4 o;
  o.x = f2bf(g[c + 0] * ((v.x - mean) * rstd) + b[c + 0]);
  o.y = f2bf(g[c + 1] * ((v.y - mean) * rstd) + b[c + 1]);
  o.z = f2bf(g[c + 2] * ((v.z - mean) * rstd) + b[c + 2]);
  o.w = f2bf(g[c + 3] * ((v.w - mean) * rstd) + b[c + 3]);
  *(ushort4*)(out + (size_t)row * 1024 + c) = o;
}

// ---- XOR swizzle (64B LDS rows, 16B slots): phys_slot = log_slot ^ sw(row),
// sw(row) = (row>>1)&3. Write side pre-swizzles the GLOBAL source col since
// global_load_lds writes linearly. 3-deep counted-vmcnt pipeline (T4).
// ---------------- GEMM 256^2: 8 waves (2x4), wave tile 128x64 --------------
// EPI 0: QKV fused (N=3072). EPI 2: gelu -> bf16 (FFN1).
DEV void stage256(const u16* __restrict__ A, const u16* __restrict__ Bt,
                  int bm, int bn, int K, int kof, u16 (*Al)[32],
                  u16 (*Bl)[32], int w, int lane) {
  const int srow = lane >> 2;
  const int scol = ((lane & 3) ^ ((lane >> 3) & 3)) * 8;  // swizzled source
#pragma unroll
  for (int p = 0; p < 2; ++p) {
    const int r0 = (w * 2 + p) * 16;  // 0..240
    GLOAD_LDS16(A + (size_t)(bm + r0 + srow) * K + kof + scol, &Al[r0][0]);
    GLOAD_LDS16(Bt + (size_t)(bn + r0 + srow) * K + kof + scol, &Bl[r0][0]);
  }
}

DEV void step256(const u16 (*Al)[32], const u16 (*Bl)[32],
                 f32x4 (&acc)[8][4], int wm, int wn, int lr, int lg) {
  const int cs = (lg ^ ((lr >> 1) & 3)) * 8;  // swizzled read col
  s16x8 af[8], bf[4];
#pragma unroll
  for (int i = 0; i < 8; ++i)
    af[i] = *(const s16x8*)&Al[wm + i * 16 + lr][cs];
#pragma unroll
  for (int j = 0; j < 4; ++j)
    bf[j] = *(const s16x8*)&Bl[wn + j * 16 + lr][cs];
#pragma unroll
  for (int i = 0; i < 8; ++i)
#pragma unroll
    for (int j = 0; j < 4; ++j)
      acc[i][j] = MFMA16(af[i], bf[j], acc[i][j], 0, 0, 0);
}

template <int EPI>
__global__ __launch_bounds__(512, 2) void pipe256_kernel(
    const u16* __restrict__ A, const u16* __restrict__ Bt,
    const float* __restrict__ bias, void* __restrict__ Cv, int M, int N,
    int K) {
  __shared__ __align__(16) u16 Al[3][256][32];
  __shared__ __align__(16) u16 Bl[3][256][32];
  const int t = threadIdx.x;
  const int lane = t & 63, w = t >> 6;          // 8 waves
  const int wm = (w >> 2) * 128, wn = (w & 3) * 64;
  int bid = blockIdx.y * gridDim.x + blockIdx.x;
  const int q8 = (gridDim.x * gridDim.y) >> 3;
  bid = (bid & 7) * q8 + (bid >> 3);
  const int bm = (bid / gridDim.x) * 256, bn = (bid % gridDim.x) * 256;
  const int lr = lane & 15, lg = lane >> 4;
  f32x4 acc[8][4] = {};
  const int nkt = K >> 5;

  stage256(A, Bt, bm, bn, K, 0, Al[0], Bl[0], w, lane);
  stage256(A, Bt, bm, bn, K, 32, Al[1], Bl[1], w, lane);
  for (int kt = 0; kt < nkt; ++kt) {
    if (kt == nkt - 1) WAIT_VM(0);
    else               WAIT_VM(4);
    __builtin_amdgcn_s_barrier();
    if (kt + 2 < nkt) {
      const int nb = (kt + 2) % 3;
      stage256(A, Bt, bm, bn, K, (kt + 2) << 5, Al[nb], Bl[nb], w, lane);
    }
    step256(Al[kt % 3], Bl[kt % 3], acc, wm, wn, lr, lg);
  }

#pragma unroll
  for (int i = 0; i < 8; ++i) {
    const int row = bm + wm + i * 16 + lg * 4;  // + e
#pragma unroll
    for (int j = 0; j < 4; ++j) {
      const int col = bn + wn + j * 16 + lr;
      if (EPI == 0) {
        const int bb = row >> 11, sloc = row & 2047;
        const int which = col >> 10, n = col & 1023;
        const int hh = n >> 6, dd = n & 63;
        u16* qbuf = (u16*)Cv;
        if (which == 2) {  // V transposed [bh][64][2048]
          ushort4 o;
          o.x = f2bf(acc[i][j][0]); o.y = f2bf(acc[i][j][1]);
          o.z = f2bf(acc[i][j][2]); o.w = f2bf(acc[i][j][3]);
          *(ushort4*)(qbuf + 8388608 +
                      (size_t)((bb * 16 + hh) * 64 + dd) * 2048 + sloc) = o;
        } else {
          // q pre-scaled by (1/8)*log2(e) so attention runs in exp2 space
          const float sc = (which == 0) ? 0.18033688011112042f : 1.0f;
          u16* dst = qbuf + (size_t)which * 4194304 +
                     ((size_t)(bb * 16 + hh) * 2048 + sloc) * 64 + dd;
#pragma unroll
          for (int e = 0; e < 4; ++e) dst[(size_t)e * 64] = f2bf(acc[i][j][e] * sc);
        }
      } else {
        u16* C = (u16*)Cv;
        const float bs = bias[col];
#pragma unroll
        for (int e = 0; e < 4; ++e)
          C[(size_t)(row + e) * N + col] = f2bf(gelu_tanh(acc[i][j][e] + bs));
      }
    }
  }
}

// ---------------- GEMM 64^2 pipelined: proj / FFN2 (bias+residual) ---------
DEV void stage64(const u16* __restrict__ A, const u16* __restrict__ Bt,
                 int bm, int bn, int K, int kof, u16 (*Al)[32],
                 u16 (*Bl)[32], int w, int lane) {
  const int srow = lane >> 2;
  const int scol = ((lane & 3) ^ ((lane >> 3) & 3)) * 8;
  const int r0 = w << 4;
  GLOAD_LDS16(A + (size_t)(bm + r0 + srow) * K + kof + scol, &Al[r0][0]);
  GLOAD_LDS16(Bt + (size_t)(bn + r0 + srow) * K + kof + scol, &Bl[r0][0]);
}

DEV void step64(const u16 (*Al)[32], const u16 (*Bl)[32],
                f32x4 (&acc)[2][2], int wm, int wn, int lr, int lg) {
  const int cs = (lg ^ ((lr >> 1) & 3)) * 8;
  s16x8 af[2], bf[2];
#pragma unroll
  for (int i = 0; i < 2; ++i) {
    af[i] = *(const s16x8*)&Al[wm + i * 16 + lr][cs];
    bf[i] = *(const s16x8*)&Bl[wn + i * 16 + lr][cs];
  }
#pragma unroll
  for (int i = 0; i < 2; ++i)
#pragma unroll
    for (int j = 0; j < 2; ++j)
      acc[i][j] = MFMA16(af[i], bf[j], acc[i][j], 0, 0, 0);
}

__global__ __launch_bounds__(256) void pipe64_kernel(
    const u16* __restrict__ A, const u16* __restrict__ Bt,
    const float* __restrict__ bias, const float* __restrict__ res,
    float* __restrict__ C, int M, int N, int K) {
  __shared__ __align__(16) u16 Al[3][64][32];
  __shared__ __align__(16) u16 Bl[3][64][32];
  const int t = threadIdx.x;
  const int lane = t & 63, w = t >> 6;
  const int wm = (w >> 1) * 32, wn = (w & 1) * 32;
  int bid = blockIdx.y * gridDim.x + blockIdx.x;
  const int q8 = (gridDim.x * gridDim.y) >> 3;
  bid = (bid & 7) * q8 + (bid >> 3);
  const int bm = (bid / gridDim.x) * 64, bn = (bid % gridDim.x) * 64;
  const int lr = lane & 15, lg = lane >> 4;
  f32x4 acc[2][2] = {};
  const int nkt = K >> 5;

  stage64(A, Bt, bm, bn, K, 0, Al[0], Bl[0], w, lane);
  stage64(A, Bt, bm, bn, K, 32, Al[1], Bl[1], w, lane);
  for (int kt = 0; kt < nkt; ++kt) {
    if (kt == nkt - 1) WAIT_VM(0);
    else               WAIT_VM(2);
    __builtin_amdgcn_s_barrier();
    if (kt + 2 < nkt) {
      const int nb = (kt + 2) % 3;
      stage64(A, Bt, bm, bn, K, (kt + 2) << 5, Al[nb], Bl[nb], w, lane);
    }
    step64(Al[kt % 3], Bl[kt % 3], acc, wm, wn, lr, lg);
  }

#pragma unroll
  for (int i = 0; i < 2; ++i) {
    const int row = bm + wm + i * 16 + lg * 4;  // + e
#pragma unroll
    for (int j = 0; j < 2; ++j) {
      const int col = bn + wn + j * 16 + lr;
      const float bs = bias[col];
#pragma unroll
      for (int e = 0; e < 4; ++e)
        C[(size_t)(row + e) * N + col] =
            acc[i][j][e] + bs + res[(size_t)(row + e) * N + col];
    }
  }
}

// ---------------- Flash attention: 32x32 swapped, zero-LDS -----------------
// Static-shift softmax (exp2-space shift M=2, exact by shift-invariance).
DEV float vsum16(const f32x16& v) {
  float a = v[0] + v[1], b = v[2] + v[3];
  float c = v[4] + v[5], d = v[6] + v[7];
  float e = v[8] + v[9], f = v[10] + v[11];
  float g = v[12] + v[13], h = v[14] + v[15];
  a += b; c += d; e += f; g += h;
  return (a + c) + (e + g);
}

struct A32 {
  s16x8 q[4];
  f32x16 o0, o1;
  float l;
};

struct TileRegs { s16x8 k0[4], k1[4], v0[4], v1[4]; };

DEV void tld(TileRegs& r, int k0, const u16* Kb, const u16* Vb, int la,
             int hi) {
#pragma unroll
  for (int c = 0; c < 4; ++c) {
    r.k0[c] = ld8(Kb + (size_t)(k0 + la) * 64 + c * 16 + hi * 8);
    r.k1[c] = ld8(Kb + (size_t)(k0 + 32 + la) * 64 + c * 16 + hi * 8);
    r.v0[c] = ld8(Vb + (size_t)la * 2048 + k0 + c * 16 + hi * 8);
    r.v1[c] = ld8(Vb + (size_t)(32 + la) * 2048 + k0 + c * 16 + hi * 8);
  }
}

DEV void pv_accum(A32& st, const s16x8* v0, const s16x8* v1,
                  const f32x16& s0, const f32x16& s1, int nh, int hi) {
#pragma unroll
  for (int half = 0; half < 2; ++half) {
    if (half >= nh) break;
    u32 w[8];
#pragma unroll
    for (int i = 0; i < 8; ++i)
      w[i] = half ? cvtpk(s1[2 * i], s1[2 * i + 1])
                  : cvtpk(s0[2 * i], s0[2 * i + 1]);
#pragma unroll
    for (int kp = 0; kp < 2; ++kp) {
      const u32 w0 = w[4 * kp + 0], w1 = w[4 * kp + 1];
      const u32 w2 = w[4 * kp + 2], w3 = w[4 * kp + 3];
      const u32 t0 = hi ? w0 : w2, t1 = hi ? w1 : w3;
      const u32 x0 = (u32)__shfl_xor((int)t0, 32);
      const u32 x1 = (u32)__shfl_xor((int)t1, 32);
      union { u32 u[4]; s16x8 v; } bb;
      bb.u[0] = hi ? x0 : w0;
      bb.u[1] = hi ? x1 : w1;
      bb.u[2] = hi ? w2 : x0;
      bb.u[3] = hi ? w3 : x1;
      const int kc = half * 2 + kp;
      st.o0 = MFMA32(v0[kc], bb.v, st.o0, 0, 0, 0);
      st.o1 = MFMA32(v1[kc], bb.v, st.o1, 0, 0, 0);
    }
  }
}

// interior (unmasked) body on preloaded tile regs; static shift M=2
DEV void bcomp0(A32& st, const TileRegs& tr, int la, int hi) {
  f32x16 s0, s1;
#pragma unroll
  for (int r = 0; r < 16; ++r) { s0[r] = 0.f; s1[r] = 0.f; }
#pragma unroll
  for (int c = 0; c < 4; ++c) s0 = MFMA32(tr.k0[c], st.q[c], s0, 0, 0, 0);
#pragma unroll
  for (int c = 0; c < 4; ++c) s1 = MFMA32(tr.k1[c], st.q[c], s1, 0, 0, 0);
#pragma unroll
  for (int r = 0; r < 16; ++r) s0[r] = exp2f(s0[r] - 2.0f);
#pragma unroll
  for (int r = 0; r < 16; ++r) s1[r] = exp2f(s1[r] - 2.0f);
  float rs = vsum16(s0) + vsum16(s1);
  rs += __shfl_xor(rs, 32);
  st.l += rs;
  pv_accum(st, tr.v0, tr.v1, s0, s1, 2, hi);
}

// self-loading masked tail bodies (MODE 1: full tile, mask upper 32;
// MODE 2: lower 32 keys only)
template <int MODE>
DEV void body32(A32& st, int k0, const u16* Kb, const u16* Vb, int la,
                int hi) {
  s16x8 ka0[4], ka1[4];
#pragma unroll
  for (int c = 0; c < 4; ++c)
    ka0[c] = ld8(Kb + (size_t)(k0 + la) * 64 + c * 16 + hi * 8);
  if (MODE != 2)
#pragma unroll
    for (int c = 0; c < 4; ++c)
      ka1[c] = ld8(Kb + (size_t)(k0 + 32 + la) * 64 + c * 16 + hi * 8);
  f32x16 s0, s1;
#pragma unroll
  for (int r = 0; r < 16; ++r) { s0[r] = 0.f; s1[r] = 0.f; }
#pragma unroll
  for (int c = 0; c < 4; ++c) s0 = MFMA32(ka0[c], st.q[c], s0, 0, 0, 0);
  if (MODE != 2)
#pragma unroll
    for (int c = 0; c < 4; ++c) s1 = MFMA32(ka1[c], st.q[c], s1, 0, 0, 0);
  const int nkc = (MODE == 2) ? 2 : 4;
  s16x8 va0[4], va1[4];
#pragma unroll
  for (int kc = 0; kc < 4; ++kc)
    if (kc < nkc) {
      va0[kc] = ld8(Vb + (size_t)la * 2048 + k0 + kc * 16 + hi * 8);
      va1[kc] = ld8(Vb + (size_t)(32 + la) * 2048 + k0 + kc * 16 + hi * 8);
    }
  if (MODE == 1) {
#pragma unroll
    for (int r = 0; r < 16; ++r) {
      const int kl = (r & 3) + 8 * (r >> 2) + 4 * hi;
      if (kl > la) s1[r] = -INFINITY;
    }
  }
  if (MODE == 2) {
#pragma unroll
    for (int r = 0; r < 16; ++r) {
      const int kl = (r & 3) + 8 * (r >> 2) + 4 * hi;
      if (kl > la) s0[r] = -INFINITY;
    }
  }
#pragma unroll
  for (int r = 0; r < 16; ++r) s0[r] = exp2f(s0[r] - 2.0f);
  if (MODE != 2)
#pragma unroll
    for (int r = 0; r < 16; ++r) s1[r] = exp2f(s1[r] - 2.0f);
  float rs = vsum16(s0);
  if (MODE != 2) rs += vsum16(s1);
  rs += __shfl_xor(rs, 32);
  st.l += rs;
  pv_accum(st, va0, va1, s0, s1, (MODE == 2) ? 1 : 2, hi);
}

DEV void a32_init(A32& st, const u16* Qbase, int qs, int la, int hi) {
#pragma unroll
  for (int c = 0; c < 4; ++c)
    st.q[c] = ld8(Qbase + (size_t)(qs + la) * 64 + c * 16 + hi * 8);
#pragma unroll
  for (int r = 0; r < 16; ++r) { st.o0[r] = 0.f; st.o1[r] = 0.f; }
  st.l = 0.f;
}

DEV void a32_fin(const A32& st, u16* __restrict__ ctx, int bh, int qs, int la,
                 int hi) {
  const int bb = bh >> 4, hh = bh & 15;
  const float inv = 1.0f / st.l;
  u16* crow = ctx + (size_t)(bb * 2048 + qs + la) * 1024 + hh * 64;
#pragma unroll
  for (int r = 0; r < 16; r += 2) {
    const int d = (r & 3) + 8 * (r >> 2) + 4 * hi;
    *(u32*)(crow + d) = cvtpk(st.o0[r] * inv, st.o0[r + 1] * inv);
    *(u32*)(crow + 32 + d) = cvtpk(st.o1[r] * inv, st.o1[r + 1] * inv);
  }
}

__global__ __launch_bounds__(64) void attn_kernel(
    const u16* __restrict__ Qg, const u16* __restrict__ Kg,
    const u16* __restrict__ Vt, u16* __restrict__ ctx) {
  const int lane = threadIdx.x & 63;
  const int la = lane & 31, hi = lane >> 5;
  // XCD-affine decode: bid = j*8 + (bh&7); head's 32 blocks share an XCD.
  const int bid = blockIdx.x;
  const int j = bid >> 3;
  const int bh = ((j >> 5) << 3) | (bid & 7);
  const int tA = j & 31;                // 0..31 (light chunk)
  const int tB = 63 - tA;               // heavy chunk
  const int qsA = tA * 32, qsB = tB * 32;
  const int nfA = tA >> 1, nfB = tB >> 1;  // interior tiles (nfA <= nfB)
  const size_t baseK = (size_t)bh * 2048 * 64;
  const size_t baseV = (size_t)bh * 64 * 2048;
  const u16* Kb = Kg + baseK;
  const u16* Vb = Vt + baseV;

  A32 A, B;
  a32_init(A, Qg + baseK, qsA, la, hi);
  a32_init(B, Qg + baseK, qsB, la, hi);

  TileRegs r0, r1;
  tld(r0, 0, Kb, Vb, la, hi);
  int kt = 0;
  while (kt < nfB) {
    if (kt + 1 < nfB) tld(r1, (kt + 1) * 64, Kb, Vb, la, hi);
    bcomp0(B, r0, la, hi);
    if (kt < nfA) bcomp0(A, r0, la, hi);
    ++kt;
    if (kt >= nfB) break;
    if (kt + 1 < nfB) tld(r0, (kt + 1) * 64, Kb, Vb, la, hi);
    bcomp0(B, r1, la, hi);
    if (kt < nfA) bcomp0(A, r1, la, hi);
    ++kt;
  }

  if (tA & 1) body32<1>(A, nfA * 64, Kb, Vb, la, hi);
  else        body32<2>(A, nfA * 64, Kb, Vb, la, hi);
  if (tB & 1) body32<1>(B, nfB * 64, Kb, Vb, la, hi);
  else        body32<2>(B, nfB * 64, Kb, Vb, la, hi);
  a32_fin(A, ctx, bh, qsA, la, hi);
  a32_fin(B, ctx, bh, qsB, la, hi);
}

// ---------------------------------------------------------------------------
extern "C" void kernel_launch(void* const* d_in, const int* in_sizes, int n_in,
                              void* d_out, int out_size, void* d_ws,
                              size_t ws_size, hipStream_t stream) {
  const float* x  = (const float*)d_in[0];
  const float* wq = (const float*)d_in[1];
  const float* wk = (const float*)d_in[2];
  const float* wv = (const float*)d_in[3];
  const float* wo = (const float*)d_in[4];
  const float* bo = (const float*)d_in[5];
  const float* w1 = (const float*)d_in[6];
  const float* b1 = (const float*)d_in[7];
  const float* w2 = (const float*)d_in[8];
  const float* b2 = (const float*)d_in[9];
  const float* g1 = (const float*)d_in[10];
  const float* s1 = (const float*)d_in[11];
  const float* g2 = (const float*)d_in[12];
  const float* s2 = (const float*)d_in[13];
  float* out = (float*)d_out;

  const size_t MB = (size_t)1 << 20;
  char* p = (char*)d_ws;
  u16* hb    = (u16*)(p + 0 * MB);    // LN1 out (dead after QKV)
  u16* qbuf  = (u16*)(p + 8 * MB);    // q | k [32][2048][64], vt [32][64][2048]
  u16* ctxb  = (u16*)(p + 32 * MB);
  float* x2  = (float*)(p + 40 * MB); // residual fp32 (16MB)
  u16* h2b   = (u16*)(p + 56 * MB);   // LN2 out (8MB)
  u16* qkvw  = (u16*)(p + 64 * MB);   // [3072][1024] packed Wq/Wk/Wv^T (6MB)
  u16* wot   = (u16*)(p + 70 * MB);
  u16* w1t   = (u16*)(p + 72 * MB);
  u16* w2t   = (u16*)(p + 80 * MB);
  u16* gb    = (u16*)(p + 0 * MB);    // gelu out, aliases hb/qbuf (32MB)

  const dim3 blk(256);
  tconv_all<<<dim3(3072), blk, 0, stream>>>(wq, wk, wv, wo, w1, w2, qkvw, wot,
                                            w1t, w2t);
  ln_kernel<<<4096, blk, 0, stream>>>(x, g1, s1, hb);
  pipe256_kernel<0><<<dim3(12, 16), dim3(512), 0, stream>>>(
      hb, qkvw, nullptr, qbuf, 4096, 3072, 1024);
  attn_kernel<<<dim3(1024), dim3(64), 0, stream>>>(
      qbuf, qbuf + 4194304, qbuf + 8388608, ctxb);
  pipe64_kernel<<<dim3(16, 64), blk, 0, stream>>>(ctxb, wot, bo, x, x2, 4096,
                                                  1024, 1024);
  ln_kernel<<<4096, blk, 0, stream>>>(x2, g2, s2, h2b);
  pipe256_kernel<2><<<dim3(16, 16), dim3(512), 0, stream>>>(
      h2b, w1t, b1, gb, 4096, 4096, 1024);
  pipe64_kernel<<<dim3(16, 64), blk, 0, stream>>>(gb, w2t, b2, x2, out, 4096,
                                                  1024, 4096);
}

// Round 18
// 265.155 us; speedup vs baseline: 1.0354x; 1.0354x over previous
//
#include <hip/hip_runtime.h>

// TransformerBlock: B=2, S=2048, D=1024, H=16, dh=64, FFN=4096.
// Round 18: round-16 config (pipe128 QKV/FFN1) + coalesced QKV q/k epilogue
// via in-wave LDS transpose (1KB contiguous stores).

typedef __attribute__((ext_vector_type(8))) short s16x8;
typedef __attribute__((ext_vector_type(4))) float f32x4;
typedef __attribute__((ext_vector_type(16))) float f32x16;
typedef unsigned short u16;
typedef unsigned int u32;

#define DEV static __device__ __forceinline__
#define MFMA16 __builtin_amdgcn_mfma_f32_16x16x32_bf16
#define MFMA32 __builtin_amdgcn_mfma_f32_32x32x16_bf16
#define GLOAD_LDS16(gp, lp)                                         \
  __builtin_amdgcn_global_load_lds(                                 \
      (const __attribute__((address_space(1))) void*)(gp),          \
      (__attribute__((address_space(3))) void*)(lp), 16, 0, 0)
#define WAIT_VM(N) asm volatile("s_waitcnt vmcnt(" #N ")" ::: "memory")

DEV u16 f2bf(float f) {
  union { float f; unsigned u; } c; c.f = f;
  unsigned u = c.u;
  u += 0x7fff + ((u >> 16) & 1);   // RNE
  return (u16)(u >> 16);
}

DEV u32 cvtpk(float lo, float hi) {  // packed f32x2 -> bf16x2 (RNE)
  u32 r;
  asm("v_cvt_pk_bf16_f32 %0, %1, %2" : "=v"(r) : "v"(lo), "v"(hi));
  return r;
}

DEV float frcp(float x) {
  float r;
  asm("v_rcp_f32 %0, %1" : "=v"(r) : "v"(x));
  return r;
}

// gelu(v) = v * sigmoid(2 c0 (v + a v^3)) = v / (1 + exp2(K v (1 + a v^2)))
DEV float gelu_tanh(float v) {
  const float K = -2.3021171648f;   // -2 * log2(e) * sqrt(2/pi)
  const float a = 0.044715f;
  const float w = v * v;
  const float q = fmaf(a, w, 1.0f);
  const float z = exp2f(K * v * q);
  return v * frcp(1.0f + z);
}

DEV s16x8 ld8(const u16* p) { return *(const s16x8*)p; }

// ---------- fused transpose+convert for all 6 weights ----------------------
DEV void tconv_tile(const float* __restrict__ W, u16* __restrict__ Wt, int K,
                    int N, int bx, int by, int t) {
  __shared__ u16 T[64][80];
  const int n0 = bx * 64, k0 = by * 64;
  const int kr = t >> 4, nc = (t & 15) * 4;
#pragma unroll
  for (int p = 0; p < 4; ++p) {
    const int k = p * 16 + kr;
    float4 v = *(const float4*)(W + (size_t)(k0 + k) * N + n0 + nc);
    T[nc + 0][k] = f2bf(v.x);
    T[nc + 1][k] = f2bf(v.y);
    T[nc + 2][k] = f2bf(v.z);
    T[nc + 3][k] = f2bf(v.w);
  }
  __syncthreads();
  const int nr = t >> 2, kc = (t & 3) * 16;
  *(s16x8*)(Wt + (size_t)(n0 + nr) * K + k0 + kc) = *(const s16x8*)&T[nr][kc];
  *(s16x8*)(Wt + (size_t)(n0 + nr) * K + k0 + kc + 8) =
      *(const s16x8*)&T[nr][kc + 8];
}

__global__ __launch_bounds__(256) void tconv_all(
    const float* __restrict__ wq, const float* __restrict__ wk,
    const float* __restrict__ wv, const float* __restrict__ wo,
    const float* __restrict__ w1, const float* __restrict__ w2,
    u16* __restrict__ qkvw, u16* __restrict__ wot, u16* __restrict__ w1t,
    u16* __restrict__ w2t) {
  const int idx = blockIdx.x, t = threadIdx.x;
  if (idx < 768) {
    const int which = idx >> 8, r = idx & 255;
    const float* W = which == 0 ? wq : (which == 1 ? wk : wv);
    tconv_tile(W, qkvw + which * 1048576, 1024, 1024, r & 15, r >> 4, t);
  } else if (idx < 1024) {
    const int r = idx - 768;
    tconv_tile(wo, wot, 1024, 1024, r & 15, r >> 4, t);
  } else if (idx < 2048) {
    const int r = idx - 1024;
    tconv_tile(w1, w1t, 1024, 4096, r & 63, r >> 6, t);
  } else {
    const int r = idx - 2048;
    tconv_tile(w2, w2t, 4096, 1024, r & 15, r >> 4, t);
  }
}

// ---------------- LayerNorm: fp32 [rows,1024] -> bf16 [rows,1024] ----------
__global__ __launch_bounds__(256) void ln_kernel(
    const float* __restrict__ x, const float* __restrict__ g,
    const float* __restrict__ b, u16* __restrict__ out) {
  const int row = blockIdx.x;
  const int t = threadIdx.x;
  const float* xr = x + (size_t)row * 1024;
  float4 v = *(const float4*)(xr + t * 4);
  float s = v.x + v.y + v.z + v.w;
  float ss = v.x * v.x + v.y * v.y + v.z * v.z + v.w * v.w;
#pragma unroll
  for (int off = 1; off < 64; off <<= 1) {
    s += __shfl_xor(s, off);
    ss += __shfl_xor(ss, off);
  }
  __shared__ float sb[4], ssb[4];
  const int w = t >> 6;
  if ((t & 63) == 0) { sb[w] = s; ssb[w] = ss; }
  __syncthreads();
  s = sb[0] + sb[1] + sb[2] + sb[3];
  ss = ssb[0] + ssb[1] + ssb[2] + ssb[3];
  const float mean = s * (1.0f / 1024.0f);
  const float var = ss * (1.0f / 1024.0f) - mean * mean;
  const float rstd = rsqrtf(var + 1e-5f);
  const int c = t * 4;
  ushort4 o;
  o.x = f2bf(g[c + 0] * ((v.x - mean) * rstd) + b[c + 0]);
  o.y = f2bf(g[c + 1] * ((v.y - mean) * rstd) + b[c + 1]);
  o.z = f2bf(g[c + 2] * ((v.z - mean) * rstd) + b[c + 2]);
  o.w = f2bf(g[c + 3] * ((v.w - mean) * rstd) + b[c + 3]);
  *(ushort4*)(out + (size_t)row * 1024 + c) = o;
}

// ---- XOR swizzle (64B LDS rows, 16B slots): phys_slot = log_slot ^ sw(row),
// sw(row) = (row>>1)&3. Write side pre-swizzles the GLOBAL source col since
// global_load_lds writes linearly. 3-deep counted-vmcnt pipeline (T4).
// ---------------- GEMM 128^2: QKV (EPI0) / FFN1 (EPI2) ---------------------
DEV void stage128(const u16* __restrict__ A, const u16* __restrict__ Bt,
                  int bm, int bn, int K, int kof, u16 (*Al)[32],
                  u16 (*Bl)[32], int w, int lane) {
  const int srow = lane >> 2;
  const int scol = ((lane & 3) ^ ((lane >> 3) & 3)) * 8;  // swizzled source
#pragma unroll
  for (int p = 0; p < 2; ++p) {
    const int r0 = (w * 2 + p) * 16;
    GLOAD_LDS16(A + (size_t)(bm + r0 + srow) * K + kof + scol, &Al[r0][0]);
    GLOAD_LDS16(Bt + (size_t)(bn + r0 + srow) * K + kof + scol, &Bl[r0][0]);
  }
}

DEV void step128(const u16 (*Al)[32], const u16 (*Bl)[32],
                 f32x4 (&acc)[4][4], int wm, int wn, int lr, int lg) {
  const int cs = (lg ^ ((lr >> 1) & 3)) * 8;  // swizzled read col
  s16x8 af[4], bf[4];
#pragma unroll
  for (int i = 0; i < 4; ++i) {
    af[i] = *(const s16x8*)&Al[wm + i * 16 + lr][cs];
    bf[i] = *(const s16x8*)&Bl[wn + i * 16 + lr][cs];
  }
#pragma unroll
  for (int i = 0; i < 4; ++i)
#pragma unroll
    for (int j = 0; j < 4; ++j)
      acc[i][j] = MFMA16(af[i], bf[j], acc[i][j], 0, 0, 0);
}

template <int EPI>
__global__ __launch_bounds__(256) void pipe128_kernel(
    const u16* __restrict__ A, const u16* __restrict__ Bt,
    const float* __restrict__ bias, void* __restrict__ Cv, int M, int N,
    int K) {
  __shared__ __align__(16) u16 Al[3][128][32];
  __shared__ __align__(16) u16 Bl[3][128][32];
  const int t = threadIdx.x;
  const int lane = t & 63, w = t >> 6;
  const int wm = (w >> 1) * 64, wn = (w & 1) * 64;
  int bid = blockIdx.y * gridDim.x + blockIdx.x;
  const int q8 = (gridDim.x * gridDim.y) >> 3;
  bid = (bid & 7) * q8 + (bid >> 3);
  const int bm = (bid / gridDim.x) * 128, bn = (bid % gridDim.x) * 128;
  const int lr = lane & 15, lg = lane >> 4;
  f32x4 acc[4][4] = {};
  const int nkt = K >> 5;

  stage128(A, Bt, bm, bn, K, 0, Al[0], Bl[0], w, lane);
  stage128(A, Bt, bm, bn, K, 32, Al[1], Bl[1], w, lane);
  for (int kt = 0; kt < nkt; ++kt) {
    if (kt == nkt - 1) WAIT_VM(0);
    else               WAIT_VM(4);
    __builtin_amdgcn_s_barrier();
    if (kt + 2 < nkt) {
      const int nb = (kt + 2) % 3;
      stage128(A, Bt, bm, bn, K, (kt + 2) << 5, Al[nb], Bl[nb], w, lane);
    }
    step128(Al[kt % 3], Bl[kt % 3], acc, wm, wn, lr, lg);
  }

  if (EPI == 0) {
    // QKV epilogue. Wave tile = 64 rows x 64 cols = one head's d-range.
    __syncthreads();  // uniform: all waves; stage buffers become scratch
    const int nwv = (bn + wn) & 1023;
    const int whichW = (bn + wn) >> 10;    // uniform per wave
    const int hh = nwv >> 6;
    const int bb = (bm + wm) >> 11, sbase = (bm + wm) & 2047;
    u16* qbuf = (u16*)Cv;
    if (whichW == 2) {  // V transposed [bh][64][2048] (old path)
#pragma unroll
      for (int i = 0; i < 4; ++i) {
#pragma unroll
        for (int j = 0; j < 4; ++j) {
          const int dd = (nwv + j * 16 + lr) & 63;
          const int sloc = sbase + i * 16 + lg * 4;
          ushort4 o;
          o.x = f2bf(acc[i][j][0]); o.y = f2bf(acc[i][j][1]);
          o.z = f2bf(acc[i][j][2]); o.w = f2bf(acc[i][j][3]);
          *(ushort4*)(qbuf + 8388608 +
                      (size_t)((bb * 16 + hh) * 64 + dd) * 2048 + sloc) = o;
        }
      }
    } else {
      // q/k: LDS transpose -> coalesced 1KB stores.
      u16* scr = (w < 3) ? &Al[w][0][0] : &Bl[0][0][0];  // 8KB per wave
      const float sc = (whichW == 0) ? 0.18033688011112042f : 1.0f;
#pragma unroll
      for (int i = 0; i < 4; ++i)
#pragma unroll
        for (int j = 0; j < 4; ++j)
#pragma unroll
          for (int e = 0; e < 4; ++e) {
            const int rloc = i * 16 + lg * 4 + e;
            const int cloc = j * 16 + lr;
            const int pcol = (((cloc >> 3) ^ (rloc & 7)) << 3) | (cloc & 7);
            scr[rloc * 64 + pcol] = f2bf(acc[i][j][e] * sc);
          }
      // wave-local RAW: compiler inserts lgkmcnt before the reads below
      u16* qdst = qbuf + (size_t)whichW * 4194304 +
                  ((size_t)(bb * 16 + hh) * 2048 + sbase) * 64;
      const int rg = lane >> 3, c8 = lane & 7;
#pragma unroll
      for (int sub = 0; sub < 8; ++sub) {
        const int r = rg + sub * 8;
        const int pslot = c8 ^ (r & 7);
        s16x8 v = *(const s16x8*)&scr[r * 64 + pslot * 8];
        *(s16x8*)(qdst + (size_t)r * 64 + c8 * 8) = v;
      }
    }
  } else {
#pragma unroll
    for (int i = 0; i < 4; ++i) {
      const int row = bm + wm + i * 16 + lg * 4;  // + e
#pragma unroll
      for (int j = 0; j < 4; ++j) {
        const int col = bn + wn + j * 16 + lr;
        u16* C = (u16*)Cv;
        const float bs = bias[col];
#pragma unroll
        for (int e = 0; e < 4; ++e)
          C[(size_t)(row + e) * N + col] = f2bf(gelu_tanh(acc[i][j][e] + bs));
      }
    }
  }
}

// ---------------- GEMM 64^2 pipelined: proj / FFN2 (bias+residual) ---------
DEV void stage64(const u16* __restrict__ A, const u16* __restrict__ Bt,
                 int bm, int bn, int K, int kof, u16 (*Al)[32],
                 u16 (*Bl)[32], int w, int lane) {
  const int srow = lane >> 2;
  const int scol = ((lane & 3) ^ ((lane >> 3) & 3)) * 8;
  const int r0 = w << 4;
  GLOAD_LDS16(A + (size_t)(bm + r0 + srow) * K + kof + scol, &Al[r0][0]);
  GLOAD_LDS16(Bt + (size_t)(bn + r0 + srow) * K + kof + scol, &Bl[r0][0]);
}

DEV void step64(const u16 (*Al)[32], const u16 (*Bl)[32],
                f32x4 (&acc)[2][2], int wm, int wn, int lr, int lg) {
  const int cs = (lg ^ ((lr >> 1) & 3)) * 8;
  s16x8 af[2], bf[2];
#pragma unroll
  for (int i = 0; i < 2; ++i) {
    af[i] = *(const s16x8*)&Al[wm + i * 16 + lr][cs];
    bf[i] = *(const s16x8*)&Bl[wn + i * 16 + lr][cs];
  }
#pragma unroll
  for (int i = 0; i < 2; ++i)
#pragma unroll
    for (int j = 0; j < 2; ++j)
      acc[i][j] = MFMA16(af[i], bf[j], acc[i][j], 0, 0, 0);
}

__global__ __launch_bounds__(256) void pipe64_kernel(
    const u16* __restrict__ A, const u16* __restrict__ Bt,
    const float* __restrict__ bias, const float* __restrict__ res,
    float* __restrict__ C, int M, int N, int K) {
  __shared__ __align__(16) u16 Al[3][64][32];
  __shared__ __align__(16) u16 Bl[3][64][32];
  const int t = threadIdx.x;
  const int lane = t & 63, w = t >> 6;
  const int wm = (w >> 1) * 32, wn = (w & 1) * 32;
  int bid = blockIdx.y * gridDim.x + blockIdx.x;
  const int q8 = (gridDim.x * gridDim.y) >> 3;
  bid = (bid & 7) * q8 + (bid >> 3);
  const int bm = (bid / gridDim.x) * 64, bn = (bid % gridDim.x) * 64;
  const int lr = lane & 15, lg = lane >> 4;
  f32x4 acc[2][2] = {};
  const int nkt = K >> 5;

  stage64(A, Bt, bm, bn, K, 0, Al[0], Bl[0], w, lane);
  stage64(A, Bt, bm, bn, K, 32, Al[1], Bl[1], w, lane);
  for (int kt = 0; kt < nkt; ++kt) {
    if (kt == nkt - 1) WAIT_VM(0);
    else               WAIT_VM(2);
    __builtin_amdgcn_s_barrier();
    if (kt + 2 < nkt) {
      const int nb = (kt + 2) % 3;
      stage64(A, Bt, bm, bn, K, (kt + 2) << 5, Al[nb], Bl[nb], w, lane);
    }
    step64(Al[kt % 3], Bl[kt % 3], acc, wm, wn, lr, lg);
  }

#pragma unroll
  for (int i = 0; i < 2; ++i) {
    const int row = bm + wm + i * 16 + lg * 4;  // + e
#pragma unroll
    for (int j = 0; j < 2; ++j) {
      const int col = bn + wn + j * 16 + lr;
      const float bs = bias[col];
#pragma unroll
      for (int e = 0; e < 4; ++e)
        C[(size_t)(row + e) * N + col] =
            acc[i][j][e] + bs + res[(size_t)(row + e) * N + col];
    }
  }
}

// ---------------- Flash attention: 32x32 swapped, zero-LDS -----------------
// Static-shift softmax (exp2-space shift M=2, exact by shift-invariance).
DEV float vsum16(const f32x16& v) {
  float a = v[0] + v[1], b = v[2] + v[3];
  float c = v[4] + v[5], d = v[6] + v[7];
  float e = v[8] + v[9], f = v[10] + v[11];
  float g = v[12] + v[13], h = v[14] + v[15];
  a += b; c += d; e += f; g += h;
  return (a + c) + (e + g);
}

struct A32 {
  s16x8 q[4];
  f32x16 o0, o1;
  float l;
};

struct TileRegs { s16x8 k0[4], k1[4], v0[4], v1[4]; };

DEV void tld(TileRegs& r, int k0, const u16* Kb, const u16* Vb, int la,
             int hi) {
#pragma unroll
  for (int c = 0; c < 4; ++c) {
    r.k0[c] = ld8(Kb + (size_t)(k0 + la) * 64 + c * 16 + hi * 8);
    r.k1[c] = ld8(Kb + (size_t)(k0 + 32 + la) * 64 + c * 16 + hi * 8);
    r.v0[c] = ld8(Vb + (size_t)la * 2048 + k0 + c * 16 + hi * 8);
    r.v1[c] = ld8(Vb + (size_t)(32 + la) * 2048 + k0 + c * 16 + hi * 8);
  }
}

DEV void pv_accum(A32& st, const s16x8* v0, const s16x8* v1,
                  const f32x16& s0, const f32x16& s1, int nh, int hi) {
#pragma unroll
  for (int half = 0; half < 2; ++half) {
    if (half >= nh) break;
    u32 w[8];
#pragma unroll
    for (int i = 0; i < 8; ++i)
      w[i] = half ? cvtpk(s1[2 * i], s1[2 * i + 1])
                  : cvtpk(s0[2 * i], s0[2 * i + 1]);
#pragma unroll
    for (int kp = 0; kp < 2; ++kp) {
      const u32 w0 = w[4 * kp + 0], w1 = w[4 * kp + 1];
      const u32 w2 = w[4 * kp + 2], w3 = w[4 * kp + 3];
      const u32 t0 = hi ? w0 : w2, t1 = hi ? w1 : w3;
      const u32 x0 = (u32)__shfl_xor((int)t0, 32);
      const u32 x1 = (u32)__shfl_xor((int)t1, 32);
      union { u32 u[4]; s16x8 v; } bb;
      bb.u[0] = hi ? x0 : w0;
      bb.u[1] = hi ? x1 : w1;
      bb.u[2] = hi ? w2 : x0;
      bb.u[3] = hi ? w3 : x1;
      const int kc = half * 2 + kp;
      st.o0 = MFMA32(v0[kc], bb.v, st.o0, 0, 0, 0);
      st.o1 = MFMA32(v1[kc], bb.v, st.o1, 0, 0, 0);
    }
  }
}

// interior (unmasked) body on preloaded tile regs; static shift M=2
DEV void bcomp0(A32& st, const TileRegs& tr, int la, int hi) {
  f32x16 s0, s1;
#pragma unroll
  for (int r = 0; r < 16; ++r) { s0[r] = 0.f; s1[r] = 0.f; }
#pragma unroll
  for (int c = 0; c < 4; ++c) s0 = MFMA32(tr.k0[c], st.q[c], s0, 0, 0, 0);
#pragma unroll
  for (int c = 0; c < 4; ++c) s1 = MFMA32(tr.k1[c], st.q[c], s1, 0, 0, 0);
#pragma unroll
  for (int r = 0; r < 16; ++r) s0[r] = exp2f(s0[r] - 2.0f);
#pragma unroll
  for (int r = 0; r < 16; ++r) s1[r] = exp2f(s1[r] - 2.0f);
  float rs = vsum16(s0) + vsum16(s1);
  rs += __shfl_xor(rs, 32);
  st.l += rs;
  pv_accum(st, tr.v0, tr.v1, s0, s1, 2, hi);
}

// self-loading masked tail bodies (MODE 1: full tile, mask upper 32;
// MODE 2: lower 32 keys only)
template <int MODE>
DEV void body32(A32& st, int k0, const u16* Kb, const u16* Vb, int la,
                int hi) {
  s16x8 ka0[4], ka1[4];
#pragma unroll
  for (int c = 0; c < 4; ++c)
    ka0[c] = ld8(Kb + (size_t)(k0 + la) * 64 + c * 16 + hi * 8);
  if (MODE != 2)
#pragma unroll
    for (int c = 0; c < 4; ++c)
      ka1[c] = ld8(Kb + (size_t)(k0 + 32 + la) * 64 + c * 16 + hi * 8);
  f32x16 s0, s1;
#pragma unroll
  for (int r = 0; r < 16; ++r) { s0[r] = 0.f; s1[r] = 0.f; }
#pragma unroll
  for (int c = 0; c < 4; ++c) s0 = MFMA32(ka0[c], st.q[c], s0, 0, 0, 0);
  if (MODE != 2)
#pragma unroll
    for (int c = 0; c < 4; ++c) s1 = MFMA32(ka1[c], st.q[c], s1, 0, 0, 0);
  const int nkc = (MODE == 2) ? 2 : 4;
  s16x8 va0[4], va1[4];
#pragma unroll
  for (int kc = 0; kc < 4; ++kc)
    if (kc < nkc) {
      va0[kc] = ld8(Vb + (size_t)la * 2048 + k0 + kc * 16 + hi * 8);
      va1[kc] = ld8(Vb + (size_t)(32 + la) * 2048 + k0 + kc * 16 + hi * 8);
    }
  if (MODE == 1) {
#pragma unroll
    for (int r = 0; r < 16; ++r) {
      const int kl = (r & 3) + 8 * (r >> 2) + 4 * hi;
      if (kl > la) s1[r] = -INFINITY;
    }
  }
  if (MODE == 2) {
#pragma unroll
    for (int r = 0; r < 16; ++r) {
      const int kl = (r & 3) + 8 * (r >> 2) + 4 * hi;
      if (kl > la) s0[r] = -INFINITY;
    }
  }
#pragma unroll
  for (int r = 0; r < 16; ++r) s0[r] = exp2f(s0[r] - 2.0f);
  if (MODE != 2)
#pragma unroll
    for (int r = 0; r < 16; ++r) s1[r] = exp2f(s1[r] - 2.0f);
  float rs = vsum16(s0);
  if (MODE != 2) rs += vsum16(s1);
  rs += __shfl_xor(rs, 32);
  st.l += rs;
  pv_accum(st, va0, va1, s0, s1, (MODE == 2) ? 1 : 2, hi);
}

DEV void a32_init(A32& st, const u16* Qbase, int qs, int la, int hi) {
#pragma unroll
  for (int c = 0; c < 4; ++c)
    st.q[c] = ld8(Qbase + (size_t)(qs + la) * 64 + c * 16 + hi * 8);
#pragma unroll
  for (int r = 0; r < 16; ++r) { st.o0[r] = 0.f; st.o1[r] = 0.f; }
  st.l = 0.f;
}

DEV void a32_fin(const A32& st, u16* __restrict__ ctx, int bh, int qs, int la,
                 int hi) {
  const int bb = bh >> 4, hh = bh & 15;
  const float inv = 1.0f / st.l;
  u16* crow = ctx + (size_t)(bb * 2048 + qs + la) * 1024 + hh * 64;
#pragma unroll
  for (int r = 0; r < 16; r += 2) {
    const int d = (r & 3) + 8 * (r >> 2) + 4 * hi;
    *(u32*)(crow + d) = cvtpk(st.o0[r] * inv, st.o0[r + 1] * inv);
    *(u32*)(crow + 32 + d) = cvtpk(st.o1[r] * inv, st.o1[r + 1] * inv);
  }
}

__global__ __launch_bounds__(64) void attn_kernel(
    const u16* __restrict__ Qg, const u16* __restrict__ Kg,
    const u16* __restrict__ Vt, u16* __restrict__ ctx) {
  const int lane = threadIdx.x & 63;
  const int la = lane & 31, hi = lane >> 5;
  // XCD-affine decode: bid = j*8 + (bh&7); head's 32 blocks share an XCD.
  const int bid = blockIdx.x;
  const int j = bid >> 3;
  const int bh = ((j >> 5) << 3) | (bid & 7);
  const int tA = j & 31;                // 0..31 (light chunk)
  const int tB = 63 - tA;               // heavy chunk
  const int qsA = tA * 32, qsB = tB * 32;
  const int nfA = tA >> 1, nfB = tB >> 1;  // interior tiles (nfA <= nfB)
  const size_t baseK = (size_t)bh * 2048 * 64;
  const size_t baseV = (size_t)bh * 64 * 2048;
  const u16* Kb = Kg + baseK;
  const u16* Vb = Vt + baseV;

  A32 A, B;
  a32_init(A, Qg + baseK, qsA, la, hi);
  a32_init(B, Qg + baseK, qsB, la, hi);

  TileRegs r0, r1;
  tld(r0, 0, Kb, Vb, la, hi);
  int kt = 0;
  while (kt < nfB) {
    if (kt + 1 < nfB) tld(r1, (kt + 1) * 64, Kb, Vb, la, hi);
    bcomp0(B, r0, la, hi);
    if (kt < nfA) bcomp0(A, r0, la, hi);
    ++kt;
    if (kt >= nfB) break;
    if (kt + 1 < nfB) tld(r0, (kt + 1) * 64, Kb, Vb, la, hi);
    bcomp0(B, r1, la, hi);
    if (kt < nfA) bcomp0(A, r1, la, hi);
    ++kt;
  }

  if (tA & 1) body32<1>(A, nfA * 64, Kb, Vb, la, hi);
  else        body32<2>(A, nfA * 64, Kb, Vb, la, hi);
  if (tB & 1) body32<1>(B, nfB * 64, Kb, Vb, la, hi);
  else        body32<2>(B, nfB * 64, Kb, Vb, la, hi);
  a32_fin(A, ctx, bh, qsA, la, hi);
  a32_fin(B, ctx, bh, qsB, la, hi);
}

// ---------------------------------------------------------------------------
extern "C" void kernel_launch(void* const* d_in, const int* in_sizes, int n_in,
                              void* d_out, int out_size, void* d_ws,
                              size_t ws_size, hipStream_t stream) {
  const float* x  = (const float*)d_in[0];
  const float* wq = (const float*)d_in[1];
  const float* wk = (const float*)d_in[2];
  const float* wv = (const float*)d_in[3];
  const float* wo = (const float*)d_in[4];
  const float* bo = (const float*)d_in[5];
  const float* w1 = (const float*)d_in[6];
  const float* b1 = (const float*)d_in[7];
  const float* w2 = (const float*)d_in[8];
  const float* b2 = (const float*)d_in[9];
  const float* g1 = (const float*)d_in[10];
  const float* s1 = (const float*)d_in[11];
  const float* g2 = (const float*)d_in[12];
  const float* s2 = (const float*)d_in[13];
  float* out = (float*)d_out;

  const size_t MB = (size_t)1 << 20;
  char* p = (char*)d_ws;
  u16* hb    = (u16*)(p + 0 * MB);    // LN1 out (dead after QKV)
  u16* qbuf  = (u16*)(p + 8 * MB);    // q | k [32][2048][64], vt [32][64][2048]
  u16* ctxb  = (u16*)(p + 32 * MB);
  float* x2  = (float*)(p + 40 * MB); // residual fp32 (16MB)
  u16* h2b   = (u16*)(p + 56 * MB);   // LN2 out (8MB)
  u16* qkvw  = (u16*)(p + 64 * MB);   // [3072][1024] packed Wq/Wk/Wv^T (6MB)
  u16* wot   = (u16*)(p + 70 * MB);
  u16* w1t   = (u16*)(p + 72 * MB);
  u16* w2t   = (u16*)(p + 80 * MB);
  u16* gb    = (u16*)(p + 0 * MB);    // gelu out, aliases hb/qbuf (32MB)

  const dim3 blk(256);
  tconv_all<<<dim3(3072), blk, 0, stream>>>(wq, wk, wv, wo, w1, w2, qkvw, wot,
                                            w1t, w2t);
  ln_kernel<<<4096, blk, 0, stream>>>(x, g1, s1, hb);
  pipe128_kernel<0><<<dim3(24, 32), blk, 0, stream>>>(hb, qkvw, nullptr, qbuf,
                                                      4096, 3072, 1024);
  attn_kernel<<<dim3(1024), dim3(64), 0, stream>>>(
      qbuf, qbuf + 4194304, qbuf + 8388608, ctxb);
  pipe64_kernel<<<dim3(16, 64), blk, 0, stream>>>(ctxb, wot, bo, x, x2, 4096,
                                                  1024, 1024);
  ln_kernel<<<4096, blk, 0, stream>>>(x2, g2, s2, h2b);
  pipe128_kernel<2><<<dim3(32, 32), blk, 0, stream>>>(h2b, w1t, b1, gb, 4096,
                                                      4096, 1024);
  pipe64_kernel<<<dim3(16, 64), blk, 0, stream>>>(gb, w2t, b2, x2, out, 4096,
                                                  1024, 4096);
}

// Round 19
// 260.156 us; speedup vs baseline: 1.0553x; 1.0192x over previous
//
#include <hip/hip_runtime.h>

// TransformerBlock: B=2, S=2048, D=1024, H=16, dh=64, FFN=4096.
// Round 19: tconv+LN1 fused into one launch; s_setprio(1) around GEMM MFMA
// clusters (T5; counted-vmcnt loop has wave role diversity). Rest = round 18.

typedef __attribute__((ext_vector_type(8))) short s16x8;
typedef __attribute__((ext_vector_type(4))) float f32x4;
typedef __attribute__((ext_vector_type(16))) float f32x16;
typedef unsigned short u16;
typedef unsigned int u32;

#define DEV static __device__ __forceinline__
#define MFMA16 __builtin_amdgcn_mfma_f32_16x16x32_bf16
#define MFMA32 __builtin_amdgcn_mfma_f32_32x32x16_bf16
#define GLOAD_LDS16(gp, lp)                                         \
  __builtin_amdgcn_global_load_lds(                                 \
      (const __attribute__((address_space(1))) void*)(gp),          \
      (__attribute__((address_space(3))) void*)(lp), 16, 0, 0)
#define WAIT_VM(N) asm volatile("s_waitcnt vmcnt(" #N ")" ::: "memory")

DEV u16 f2bf(float f) {
  union { float f; unsigned u; } c; c.f = f;
  unsigned u = c.u;
  u += 0x7fff + ((u >> 16) & 1);   // RNE
  return (u16)(u >> 16);
}

DEV u32 cvtpk(float lo, float hi) {  // packed f32x2 -> bf16x2 (RNE)
  u32 r;
  asm("v_cvt_pk_bf16_f32 %0, %1, %2" : "=v"(r) : "v"(lo), "v"(hi));
  return r;
}

DEV float frcp(float x) {
  float r;
  asm("v_rcp_f32 %0, %1" : "=v"(r) : "v"(x));
  return r;
}

// gelu(v) = v * sigmoid(2 c0 (v + a v^3)) = v / (1 + exp2(K v (1 + a v^2)))
DEV float gelu_tanh(float v) {
  const float K = -2.3021171648f;   // -2 * log2(e) * sqrt(2/pi)
  const float a = 0.044715f;
  const float w = v * v;
  const float q = fmaf(a, w, 1.0f);
  const float z = exp2f(K * v * q);
  return v * frcp(1.0f + z);
}

DEV s16x8 ld8(const u16* p) { return *(const s16x8*)p; }

// ---------- prep kernel: weight transpose/convert + LN1 (independent) ------
DEV void tconv_tile(const float* __restrict__ W, u16* __restrict__ Wt, int K,
                    int N, int bx, int by, int t) {
  __shared__ u16 T[64][80];
  const int n0 = bx * 64, k0 = by * 64;
  const int kr = t >> 4, nc = (t & 15) * 4;
#pragma unroll
  for (int p = 0; p < 4; ++p) {
    const int k = p * 16 + kr;
    float4 v = *(const float4*)(W + (size_t)(k0 + k) * N + n0 + nc);
    T[nc + 0][k] = f2bf(v.x);
    T[nc + 1][k] = f2bf(v.y);
    T[nc + 2][k] = f2bf(v.z);
    T[nc + 3][k] = f2bf(v.w);
  }
  __syncthreads();
  const int nr = t >> 2, kc = (t & 3) * 16;
  *(s16x8*)(Wt + (size_t)(n0 + nr) * K + k0 + kc) = *(const s16x8*)&T[nr][kc];
  *(s16x8*)(Wt + (size_t)(n0 + nr) * K + k0 + kc + 8) =
      *(const s16x8*)&T[nr][kc + 8];
}

DEV void ln_row(const float* __restrict__ x, const float* __restrict__ g,
                const float* __restrict__ b, u16* __restrict__ out, int row,
                int t) {
  const float* xr = x + (size_t)row * 1024;
  float4 v = *(const float4*)(xr + t * 4);
  float s = v.x + v.y + v.z + v.w;
  float ss = v.x * v.x + v.y * v.y + v.z * v.z + v.w * v.w;
#pragma unroll
  for (int off = 1; off < 64; off <<= 1) {
    s += __shfl_xor(s, off);
    ss += __shfl_xor(ss, off);
  }
  __shared__ float sb[4], ssb[4];
  const int w = t >> 6;
  if ((t & 63) == 0) { sb[w] = s; ssb[w] = ss; }
  __syncthreads();
  s = sb[0] + sb[1] + sb[2] + sb[3];
  ss = ssb[0] + ssb[1] + ssb[2] + ssb[3];
  const float mean = s * (1.0f / 1024.0f);
  const float var = ss * (1.0f / 1024.0f) - mean * mean;
  const float rstd = rsqrtf(var + 1e-5f);
  const int c = t * 4;
  ushort4 o;
  o.x = f2bf(g[c + 0] * ((v.x - mean) * rstd) + b[c + 0]);
  o.y = f2bf(g[c + 1] * ((v.y - mean) * rstd) + b[c + 1]);
  o.z = f2bf(g[c + 2] * ((v.z - mean) * rstd) + b[c + 2]);
  o.w = f2bf(g[c + 3] * ((v.w - mean) * rstd) + b[c + 3]);
  *(ushort4*)(out + (size_t)row * 1024 + c) = o;
}

__global__ __launch_bounds__(256) void prep_kernel(
    const float* __restrict__ wq, const float* __restrict__ wk,
    const float* __restrict__ wv, const float* __restrict__ wo,
    const float* __restrict__ w1, const float* __restrict__ w2,
    u16* __restrict__ qkvw, u16* __restrict__ wot, u16* __restrict__ w1t,
    u16* __restrict__ w2t, const float* __restrict__ x,
    const float* __restrict__ g1, const float* __restrict__ s1,
    u16* __restrict__ hb) {
  const int idx = blockIdx.x, t = threadIdx.x;
  if (idx < 768) {
    const int which = idx >> 8, r = idx & 255;
    const float* W = which == 0 ? wq : (which == 1 ? wk : wv);
    tconv_tile(W, qkvw + which * 1048576, 1024, 1024, r & 15, r >> 4, t);
  } else if (idx < 1024) {
    const int r = idx - 768;
    tconv_tile(wo, wot, 1024, 1024, r & 15, r >> 4, t);
  } else if (idx < 2048) {
    const int r = idx - 1024;
    tconv_tile(w1, w1t, 1024, 4096, r & 63, r >> 6, t);
  } else if (idx < 3072) {
    const int r = idx - 2048;
    tconv_tile(w2, w2t, 4096, 1024, r & 15, r >> 4, t);
  } else {
    ln_row(x, g1, s1, hb, idx - 3072, t);
  }
}

// ---------------- LayerNorm (LN2): fp32 -> bf16 ----------------------------
__global__ __launch_bounds__(256) void ln_kernel(
    const float* __restrict__ x, const float* __restrict__ g,
    const float* __restrict__ b, u16* __restrict__ out) {
  ln_row(x, g, b, out, blockIdx.x, threadIdx.x);
}

// ---- XOR swizzle (64B LDS rows, 16B slots): phys_slot = log_slot ^ sw(row),
// sw(row) = (row>>1)&3. Write side pre-swizzles the GLOBAL source col since
// global_load_lds writes linearly. 3-deep counted-vmcnt pipeline (T4).
// ---------------- GEMM 128^2: QKV (EPI0) / FFN1 (EPI2) ---------------------
DEV void stage128(const u16* __restrict__ A, const u16* __restrict__ Bt,
                  int bm, int bn, int K, int kof, u16 (*Al)[32],
                  u16 (*Bl)[32], int w, int lane) {
  const int srow = lane >> 2;
  const int scol = ((lane & 3) ^ ((lane >> 3) & 3)) * 8;  // swizzled source
#pragma unroll
  for (int p = 0; p < 2; ++p) {
    const int r0 = (w * 2 + p) * 16;
    GLOAD_LDS16(A + (size_t)(bm + r0 + srow) * K + kof + scol, &Al[r0][0]);
    GLOAD_LDS16(Bt + (size_t)(bn + r0 + srow) * K + kof + scol, &Bl[r0][0]);
  }
}

DEV void step128(const u16 (*Al)[32], const u16 (*Bl)[32],
                 f32x4 (&acc)[4][4], int wm, int wn, int lr, int lg) {
  const int cs = (lg ^ ((lr >> 1) & 3)) * 8;  // swizzled read col
  s16x8 af[4], bf[4];
#pragma unroll
  for (int i = 0; i < 4; ++i) {
    af[i] = *(const s16x8*)&Al[wm + i * 16 + lr][cs];
    bf[i] = *(const s16x8*)&Bl[wn + i * 16 + lr][cs];
  }
  __builtin_amdgcn_s_setprio(1);
#pragma unroll
  for (int i = 0; i < 4; ++i)
#pragma unroll
    for (int j = 0; j < 4; ++j)
      acc[i][j] = MFMA16(af[i], bf[j], acc[i][j], 0, 0, 0);
  __builtin_amdgcn_s_setprio(0);
}

template <int EPI>
__global__ __launch_bounds__(256) void pipe128_kernel(
    const u16* __restrict__ A, const u16* __restrict__ Bt,
    const float* __restrict__ bias, void* __restrict__ Cv, int M, int N,
    int K) {
  __shared__ __align__(16) u16 Al[3][128][32];
  __shared__ __align__(16) u16 Bl[3][128][32];
  const int t = threadIdx.x;
  const int lane = t & 63, w = t >> 6;
  const int wm = (w >> 1) * 64, wn = (w & 1) * 64;
  int bid = blockIdx.y * gridDim.x + blockIdx.x;
  const int q8 = (gridDim.x * gridDim.y) >> 3;
  bid = (bid & 7) * q8 + (bid >> 3);
  const int bm = (bid / gridDim.x) * 128, bn = (bid % gridDim.x) * 128;
  const int lr = lane & 15, lg = lane >> 4;
  f32x4 acc[4][4] = {};
  const int nkt = K >> 5;

  stage128(A, Bt, bm, bn, K, 0, Al[0], Bl[0], w, lane);
  stage128(A, Bt, bm, bn, K, 32, Al[1], Bl[1], w, lane);
  for (int kt = 0; kt < nkt; ++kt) {
    if (kt == nkt - 1) WAIT_VM(0);
    else               WAIT_VM(4);
    __builtin_amdgcn_s_barrier();
    if (kt + 2 < nkt) {
      const int nb = (kt + 2) % 3;
      stage128(A, Bt, bm, bn, K, (kt + 2) << 5, Al[nb], Bl[nb], w, lane);
    }
    step128(Al[kt % 3], Bl[kt % 3], acc, wm, wn, lr, lg);
  }

  if (EPI == 0) {
    // QKV epilogue. Wave tile = 64 rows x 64 cols = one head's d-range.
    __syncthreads();  // uniform: all waves; stage buffers become scratch
    const int nwv = (bn + wn) & 1023;
    const int whichW = (bn + wn) >> 10;    // uniform per wave
    const int hh = nwv >> 6;
    const int bb = (bm + wm) >> 11, sbase = (bm + wm) & 2047;
    u16* qbuf = (u16*)Cv;
    if (whichW == 2) {  // V transposed [bh][64][2048]
#pragma unroll
      for (int i = 0; i < 4; ++i) {
#pragma unroll
        for (int j = 0; j < 4; ++j) {
          const int dd = (nwv + j * 16 + lr) & 63;
          const int sloc = sbase + i * 16 + lg * 4;
          ushort4 o;
          o.x = f2bf(acc[i][j][0]); o.y = f2bf(acc[i][j][1]);
          o.z = f2bf(acc[i][j][2]); o.w = f2bf(acc[i][j][3]);
          *(ushort4*)(qbuf + 8388608 +
                      (size_t)((bb * 16 + hh) * 64 + dd) * 2048 + sloc) = o;
        }
      }
    } else {
      // q/k: LDS transpose -> coalesced 1KB stores.
      u16* scr = (w < 3) ? &Al[w][0][0] : &Bl[0][0][0];  // 8KB per wave
      const float sc = (whichW == 0) ? 0.18033688011112042f : 1.0f;
#pragma unroll
      for (int i = 0; i < 4; ++i)
#pragma unroll
        for (int j = 0; j < 4; ++j)
#pragma unroll
          for (int e = 0; e < 4; ++e) {
            const int rloc = i * 16 + lg * 4 + e;
            const int cloc = j * 16 + lr;
            const int pcol = (((cloc >> 3) ^ (rloc & 7)) << 3) | (cloc & 7);
            scr[rloc * 64 + pcol] = f2bf(acc[i][j][e] * sc);
          }
      u16* qdst = qbuf + (size_t)whichW * 4194304 +
                  ((size_t)(bb * 16 + hh) * 2048 + sbase) * 64;
      const int rg = lane >> 3, c8 = lane & 7;
#pragma unroll
      for (int sub = 0; sub < 8; ++sub) {
        const int r = rg + sub * 8;
        const int pslot = c8 ^ (r & 7);
        s16x8 v = *(const s16x8*)&scr[r * 64 + pslot * 8];
        *(s16x8*)(qdst + (size_t)r * 64 + c8 * 8) = v;
      }
    }
  } else {
#pragma unroll
    for (int i = 0; i < 4; ++i) {
      const int row = bm + wm + i * 16 + lg * 4;  // + e
#pragma unroll
      for (int j = 0; j < 4; ++j) {
        const int col = bn + wn + j * 16 + lr;
        u16* C = (u16*)Cv;
        const float bs = bias[col];
#pragma unroll
        for (int e = 0; e < 4; ++e)
          C[(size_t)(row + e) * N + col] = f2bf(gelu_tanh(acc[i][j][e] + bs));
      }
    }
  }
}

// ---------------- GEMM 64^2 pipelined: proj / FFN2 (bias+residual) ---------
DEV void stage64(const u16* __restrict__ A, const u16* __restrict__ Bt,
                 int bm, int bn, int K, int kof, u16 (*Al)[32],
                 u16 (*Bl)[32], int w, int lane) {
  const int srow = lane >> 2;
  const int scol = ((lane & 3) ^ ((lane >> 3) & 3)) * 8;
  const int r0 = w << 4;
  GLOAD_LDS16(A + (size_t)(bm + r0 + srow) * K + kof + scol, &Al[r0][0]);
  GLOAD_LDS16(Bt + (size_t)(bn + r0 + srow) * K + kof + scol, &Bl[r0][0]);
}

DEV void step64(const u16 (*Al)[32], const u16 (*Bl)[32],
                f32x4 (&acc)[2][2], int wm, int wn, int lr, int lg) {
  const int cs = (lg ^ ((lr >> 1) & 3)) * 8;
  s16x8 af[2], bf[2];
#pragma unroll
  for (int i = 0; i < 2; ++i) {
    af[i] = *(const s16x8*)&Al[wm + i * 16 + lr][cs];
    bf[i] = *(const s16x8*)&Bl[wn + i * 16 + lr][cs];
  }
  __builtin_amdgcn_s_setprio(1);
#pragma unroll
  for (int i = 0; i < 2; ++i)
#pragma unroll
    for (int j = 0; j < 2; ++j)
      acc[i][j] = MFMA16(af[i], bf[j], acc[i][j], 0, 0, 0);
  __builtin_amdgcn_s_setprio(0);
}

__global__ __launch_bounds__(256) void pipe64_kernel(
    const u16* __restrict__ A, const u16* __restrict__ Bt,
    const float* __restrict__ bias, const float* __restrict__ res,
    float* __restrict__ C, int M, int N, int K) {
  __shared__ __align__(16) u16 Al[3][64][32];
  __shared__ __align__(16) u16 Bl[3][64][32];
  const int t = threadIdx.x;
  const int lane = t & 63, w = t >> 6;
  const int wm = (w >> 1) * 32, wn = (w & 1) * 32;
  int bid = blockIdx.y * gridDim.x + blockIdx.x;
  const int q8 = (gridDim.x * gridDim.y) >> 3;
  bid = (bid & 7) * q8 + (bid >> 3);
  const int bm = (bid / gridDim.x) * 64, bn = (bid % gridDim.x) * 64;
  const int lr = lane & 15, lg = lane >> 4;
  f32x4 acc[2][2] = {};
  const int nkt = K >> 5;

  stage64(A, Bt, bm, bn, K, 0, Al[0], Bl[0], w, lane);
  stage64(A, Bt, bm, bn, K, 32, Al[1], Bl[1], w, lane);
  for (int kt = 0; kt < nkt; ++kt) {
    if (kt == nkt - 1) WAIT_VM(0);
    else               WAIT_VM(2);
    __builtin_amdgcn_s_barrier();
    if (kt + 2 < nkt) {
      const int nb = (kt + 2) % 3;
      stage64(A, Bt, bm, bn, K, (kt + 2) << 5, Al[nb], Bl[nb], w, lane);
    }
    step64(Al[kt % 3], Bl[kt % 3], acc, wm, wn, lr, lg);
  }

#pragma unroll
  for (int i = 0; i < 2; ++i) {
    const int row = bm + wm + i * 16 + lg * 4;  // + e
#pragma unroll
    for (int j = 0; j < 2; ++j) {
      const int col = bn + wn + j * 16 + lr;
      const float bs = bias[col];
#pragma unroll
      for (int e = 0; e < 4; ++e)
        C[(size_t)(row + e) * N + col] =
            acc[i][j][e] + bs + res[(size_t)(row + e) * N + col];
    }
  }
}

// ---------------- Flash attention: 32x32 swapped, zero-LDS -----------------
// Static-shift softmax (exp2-space shift M=2, exact by shift-invariance).
DEV float vsum16(const f32x16& v) {
  float a = v[0] + v[1], b = v[2] + v[3];
  float c = v[4] + v[5], d = v[6] + v[7];
  float e = v[8] + v[9], f = v[10] + v[11];
  float g = v[12] + v[13], h = v[14] + v[15];
  a += b; c += d; e += f; g += h;
  return (a + c) + (e + g);
}

struct A32 {
  s16x8 q[4];
  f32x16 o0, o1;
  float l;
};

struct TileRegs { s16x8 k0[4], k1[4], v0[4], v1[4]; };

DEV void tld(TileRegs& r, int k0, const u16* Kb, const u16* Vb, int la,
             int hi) {
#pragma unroll
  for (int c = 0; c < 4; ++c) {
    r.k0[c] = ld8(Kb + (size_t)(k0 + la) * 64 + c * 16 + hi * 8);
    r.k1[c] = ld8(Kb + (size_t)(k0 + 32 + la) * 64 + c * 16 + hi * 8);
    r.v0[c] = ld8(Vb + (size_t)la * 2048 + k0 + c * 16 + hi * 8);
    r.v1[c] = ld8(Vb + (size_t)(32 + la) * 2048 + k0 + c * 16 + hi * 8);
  }
}

DEV void pv_accum(A32& st, const s16x8* v0, const s16x8* v1,
                  const f32x16& s0, const f32x16& s1, int nh, int hi) {
#pragma unroll
  for (int half = 0; half < 2; ++half) {
    if (half >= nh) break;
    u32 w[8];
#pragma unroll
    for (int i = 0; i < 8; ++i)
      w[i] = half ? cvtpk(s1[2 * i], s1[2 * i + 1])
                  : cvtpk(s0[2 * i], s0[2 * i + 1]);
#pragma unroll
    for (int kp = 0; kp < 2; ++kp) {
      const u32 w0 = w[4 * kp + 0], w1 = w[4 * kp + 1];
      const u32 w2 = w[4 * kp + 2], w3 = w[4 * kp + 3];
      const u32 t0 = hi ? w0 : w2, t1 = hi ? w1 : w3;
      const u32 x0 = (u32)__shfl_xor((int)t0, 32);
      const u32 x1 = (u32)__shfl_xor((int)t1, 32);
      union { u32 u[4]; s16x8 v; } bb;
      bb.u[0] = hi ? x0 : w0;
      bb.u[1] = hi ? x1 : w1;
      bb.u[2] = hi ? w2 : x0;
      bb.u[3] = hi ? w3 : x1;
      const int kc = half * 2 + kp;
      st.o0 = MFMA32(v0[kc], bb.v, st.o0, 0, 0, 0);
      st.o1 = MFMA32(v1[kc], bb.v, st.o1, 0, 0, 0);
    }
  }
}

// interior (unmasked) body on preloaded tile regs; static shift M=2
DEV void bcomp0(A32& st, const TileRegs& tr, int la, int hi) {
  f32x16 s0, s1;
#pragma unroll
  for (int r = 0; r < 16; ++r) { s0[r] = 0.f; s1[r] = 0.f; }
#pragma unroll
  for (int c = 0; c < 4; ++c) s0 = MFMA32(tr.k0[c], st.q[c], s0, 0, 0, 0);
#pragma unroll
  for (int c = 0; c < 4; ++c) s1 = MFMA32(tr.k1[c], st.q[c], s1, 0, 0, 0);
#pragma unroll
  for (int r = 0; r < 16; ++r) s0[r] = exp2f(s0[r] - 2.0f);
#pragma unroll
  for (int r = 0; r < 16; ++r) s1[r] = exp2f(s1[r] - 2.0f);
  float rs = vsum16(s0) + vsum16(s1);
  rs += __shfl_xor(rs, 32);
  st.l += rs;
  pv_accum(st, tr.v0, tr.v1, s0, s1, 2, hi);
}

// self-loading masked tail bodies (MODE 1: full tile, mask upper 32;
// MODE 2: lower 32 keys only)
template <int MODE>
DEV void body32(A32& st, int k0, const u16* Kb, const u16* Vb, int la,
                int hi) {
  s16x8 ka0[4], ka1[4];
#pragma unroll
  for (int c = 0; c < 4; ++c)
    ka0[c] = ld8(Kb + (size_t)(k0 + la) * 64 + c * 16 + hi * 8);
  if (MODE != 2)
#pragma unroll
    for (int c = 0; c < 4; ++c)
      ka1[c] = ld8(Kb + (size_t)(k0 + 32 + la) * 64 + c * 16 + hi * 8);
  f32x16 s0, s1;
#pragma unroll
  for (int r = 0; r < 16; ++r) { s0[r] = 0.f; s1[r] = 0.f; }
#pragma unroll
  for (int c = 0; c < 4; ++c) s0 = MFMA32(ka0[c], st.q[c], s0, 0, 0, 0);
  if (MODE != 2)
#pragma unroll
    for (int c = 0; c < 4; ++c) s1 = MFMA32(ka1[c], st.q[c], s1, 0, 0, 0);
  const int nkc = (MODE == 2) ? 2 : 4;
  s16x8 va0[4], va1[4];
#pragma unroll
  for (int kc = 0; kc < 4; ++kc)
    if (kc < nkc) {
      va0[kc] = ld8(Vb + (size_t)la * 2048 + k0 + kc * 16 + hi * 8);
      va1[kc] = ld8(Vb + (size_t)(32 + la) * 2048 + k0 + kc * 16 + hi * 8);
    }
  if (MODE == 1) {
#pragma unroll
    for (int r = 0; r < 16; ++r) {
      const int kl = (r & 3) + 8 * (r >> 2) + 4 * hi;
      if (kl > la) s1[r] = -INFINITY;
    }
  }
  if (MODE == 2) {
#pragma unroll
    for (int r = 0; r < 16; ++r) {
      const int kl = (r & 3) + 8 * (r >> 2) + 4 * hi;
      if (kl > la) s0[r] = -INFINITY;
    }
  }
#pragma unroll
  for (int r = 0; r < 16; ++r) s0[r] = exp2f(s0[r] - 2.0f);
  if (MODE != 2)
#pragma unroll
    for (int r = 0; r < 16; ++r) s1[r] = exp2f(s1[r] - 2.0f);
  float rs = vsum16(s0);
  if (MODE != 2) rs += vsum16(s1);
  rs += __shfl_xor(rs, 32);
  st.l += rs;
  pv_accum(st, va0, va1, s0, s1, (MODE == 2) ? 1 : 2, hi);
}

DEV void a32_init(A32& st, const u16* Qbase, int qs, int la, int hi) {
#pragma unroll
  for (int c = 0; c < 4; ++c)
    st.q[c] = ld8(Qbase + (size_t)(qs + la) * 64 + c * 16 + hi * 8);
#pragma unroll
  for (int r = 0; r < 16; ++r) { st.o0[r] = 0.f; st.o1[r] = 0.f; }
  st.l = 0.f;
}

DEV void a32_fin(const A32& st, u16* __restrict__ ctx, int bh, int qs, int la,
                 int hi) {
  const int bb = bh >> 4, hh = bh & 15;
  const float inv = 1.0f / st.l;
  u16* crow = ctx + (size_t)(bb * 2048 + qs + la) * 1024 + hh * 64;
#pragma unroll
  for (int r = 0; r < 16; r += 2) {
    const int d = (r & 3) + 8 * (r >> 2) + 4 * hi;
    *(u32*)(crow + d) = cvtpk(st.o0[r] * inv, st.o0[r + 1] * inv);
    *(u32*)(crow + 32 + d) = cvtpk(st.o1[r] * inv, st.o1[r + 1] * inv);
  }
}

__global__ __launch_bounds__(64) void attn_kernel(
    const u16* __restrict__ Qg, const u16* __restrict__ Kg,
    const u16* __restrict__ Vt, u16* __restrict__ ctx) {
  const int lane = threadIdx.x & 63;
  const int la = lane & 31, hi = lane >> 5;
  // XCD-affine decode: bid = j*8 + (bh&7); head's 32 blocks share an XCD.
  const int bid = blockIdx.x;
  const int j = bid >> 3;
  const int bh = ((j >> 5) << 3) | (bid & 7);
  const int tA = j & 31;                // 0..31 (light chunk)
  const int tB = 63 - tA;               // heavy chunk
  const int qsA = tA * 32, qsB = tB * 32;
  const int nfA = tA >> 1, nfB = tB >> 1;  // interior tiles (nfA <= nfB)
  const size_t baseK = (size_t)bh * 2048 * 64;
  const size_t baseV = (size_t)bh * 64 * 2048;
  const u16* Kb = Kg + baseK;
  const u16* Vb = Vt + baseV;

  A32 A, B;
  a32_init(A, Qg + baseK, qsA, la, hi);
  a32_init(B, Qg + baseK, qsB, la, hi);

  TileRegs r0, r1;
  tld(r0, 0, Kb, Vb, la, hi);
  int kt = 0;
  while (kt < nfB) {
    if (kt + 1 < nfB) tld(r1, (kt + 1) * 64, Kb, Vb, la, hi);
    bcomp0(B, r0, la, hi);
    if (kt < nfA) bcomp0(A, r0, la, hi);
    ++kt;
    if (kt >= nfB) break;
    if (kt + 1 < nfB) tld(r0, (kt + 1) * 64, Kb, Vb, la, hi);
    bcomp0(B, r1, la, hi);
    if (kt < nfA) bcomp0(A, r1, la, hi);
    ++kt;
  }

  if (tA & 1) body32<1>(A, nfA * 64, Kb, Vb, la, hi);
  else        body32<2>(A, nfA * 64, Kb, Vb, la, hi);
  if (tB & 1) body32<1>(B, nfB * 64, Kb, Vb, la, hi);
  else        body32<2>(B, nfB * 64, Kb, Vb, la, hi);
  a32_fin(A, ctx, bh, qsA, la, hi);
  a32_fin(B, ctx, bh, qsB, la, hi);
}

// ---------------------------------------------------------------------------
extern "C" void kernel_launch(void* const* d_in, const int* in_sizes, int n_in,
                              void* d_out, int out_size, void* d_ws,
                              size_t ws_size, hipStream_t stream) {
  const float* x  = (const float*)d_in[0];
  const float* wq = (const float*)d_in[1];
  const float* wk = (const float*)d_in[2];
  const float* wv = (const float*)d_in[3];
  const float* wo = (const float*)d_in[4];
  const float* bo = (const float*)d_in[5];
  const float* w1 = (const float*)d_in[6];
  const float* b1 = (const float*)d_in[7];
  const float* w2 = (const float*)d_in[8];
  const float* b2 = (const float*)d_in[9];
  const float* g1 = (const float*)d_in[10];
  const float* s1 = (const float*)d_in[11];
  const float* g2 = (const float*)d_in[12];
  const float* s2 = (const float*)d_in[13];
  float* out = (float*)d_out;

  const size_t MB = (size_t)1 << 20;
  char* p = (char*)d_ws;
  u16* hb    = (u16*)(p + 0 * MB);    // LN1 out (dead after QKV)
  u16* qbuf  = (u16*)(p + 8 * MB);    // q | k [32][2048][64], vt [32][64][2048]
  u16* ctxb  = (u16*)(p + 32 * MB);
  float* x2  = (float*)(p + 40 * MB); // residual fp32 (16MB)
  u16* h2b   = (u16*)(p + 56 * MB);   // LN2 out (8MB)
  u16* qkvw  = (u16*)(p + 64 * MB);   // [3072][1024] packed Wq/Wk/Wv^T (6MB)
  u16* wot   = (u16*)(p + 70 * MB);
  u16* w1t   = (u16*)(p + 72 * MB);
  u16* w2t   = (u16*)(p + 80 * MB);
  u16* gb    = (u16*)(p + 0 * MB);    // gelu out, aliases hb/qbuf (32MB)

  const dim3 blk(256);
  prep_kernel<<<dim3(7168), blk, 0, stream>>>(wq, wk, wv, wo, w1, w2, qkvw,
                                              wot, w1t, w2t, x, g1, s1, hb);
  pipe128_kernel<0><<<dim3(24, 32), blk, 0, stream>>>(hb, qkvw, nullptr, qbuf,
                                                      4096, 3072, 1024);
  attn_kernel<<<dim3(1024), dim3(64), 0, stream>>>(
      qbuf, qbuf + 4194304, qbuf + 8388608, ctxb);
  pipe64_kernel<<<dim3(16, 64), blk, 0, stream>>>(ctxb, wot, bo, x, x2, 4096,
                                                  1024, 1024);
  ln_kernel<<<4096, blk, 0, stream>>>(x2, g2, s2, h2b);
  pipe128_kernel<2><<<dim3(32, 32), blk, 0, stream>>>(h2b, w1t, b1, gb, 4096,
                                                      4096, 1024);
  pipe64_kernel<<<dim3(16, 64), blk, 0, stream>>>(gb, w2t, b2, x2, out, 4096,
                                                  1024, 4096);
}